// Round 1
// baseline (77.332 us; speedup 1.0000x reference)
//
#include <hip/hip_runtime.h>
#include <hip/hip_fp16.h>
#include <cstdint>

#define B_SZ   1024
#define N_IN   256
#define NLAY   8
#define M_SZ   4096
#define K_SZ   16
#define NCOLS  (N_IN + 1 + NLAY * M_SZ)   // 33025
#define SCALE  4.9f
#define TPB    1024

// Pack (idx, W) into one u32: low16 = index (max 28928 < 65536), high16 = fp16(W).
__global__ void pack_kernel(const int* __restrict__ edge_idx,
                            const float* __restrict__ W,
                            uint32_t* __restrict__ packed, int n) {
    int i = blockIdx.x * blockDim.x + threadIdx.x;
    if (i < n) {
        uint32_t id = (uint32_t)edge_idx[i] & 0xFFFFu;
        __half h = __float2half_rn(W[i]);
        packed[i] = id | ((uint32_t)__half_as_ushort(h) << 16);
    }
}

// One block = 2 batch rows. Full activation history for both rows lives in LDS
// as half2 (lo = row b0, hi = row b0+1): 33025 * 4 B = 132,100 B of LDS.
template <bool PACKED>
__global__ __launch_bounds__(TPB, 4)
void ffn_kernel(const float* __restrict__ x,
                const uint32_t* __restrict__ packed,
                const int* __restrict__ edge_idx,
                const float* __restrict__ W,
                float* __restrict__ out) {
    __shared__ uint32_t vals[NCOLS];

    const int tid = threadIdx.x;
    const int b0  = blockIdx.x * 2;
    const float* __restrict__ x0 = x + (size_t)b0 * N_IN;
    const float* __restrict__ x1 = x0 + N_IN;

    // Stage x rows (+ bias col at N_IN) as half2.
    for (int j = tid; j <= N_IN; j += TPB) {
        float v0 = (j < N_IN) ? x0[j] : 1.0f;
        float v1 = (j < N_IN) ? x1[j] : 1.0f;
        __half2 h2 = __floats2half2_rn(v0, v1);
        vals[j] = *reinterpret_cast<uint32_t*>(&h2);
    }
    __syncthreads();

    const int base = N_IN + 1;
    for (int l = 0; l < NLAY; ++l) {
        for (int i = 0; i < M_SZ / TPB; ++i) {
            const int m = tid + i * TPB;
            float acc0 = 0.f, acc1 = 0.f;

            if (PACKED) {
                const uint4* p4 =
                    reinterpret_cast<const uint4*>(packed + (size_t)(l * M_SZ + m) * K_SZ);
                uint4 pw[4];
                #pragma unroll
                for (int j = 0; j < 4; ++j) pw[j] = p4[j];
                #pragma unroll
                for (int j = 0; j < 4; ++j) {
                    uint32_t w0 = pw[j].x, w1 = pw[j].y, w2 = pw[j].z, w3 = pw[j].w;
                    uint32_t words[4] = {w0, w1, w2, w3};
                    #pragma unroll
                    for (int q = 0; q < 4; ++q) {
                        uint32_t p = words[q];
                        uint32_t v = vals[p & 0xFFFFu];
                        float wf = __half2float(__ushort_as_half((unsigned short)(p >> 16)));
                        __half2 h2 = *reinterpret_cast<__half2*>(&v);
                        acc0 = fmaf(__low2float(h2), wf, acc0);
                        acc1 = fmaf(__high2float(h2), wf, acc1);
                    }
                }
            } else {
                const int4*   i4 = reinterpret_cast<const int4*>(edge_idx + (size_t)(l * M_SZ + m) * K_SZ);
                const float4* w4 = reinterpret_cast<const float4*>(W + (size_t)(l * M_SZ + m) * K_SZ);
                #pragma unroll
                for (int j = 0; j < 4; ++j) {
                    int4   ii = i4[j];
                    float4 ww = w4[j];
                    int   idxs[4] = {ii.x, ii.y, ii.z, ii.w};
                    float wts[4]  = {ww.x, ww.y, ww.z, ww.w};
                    #pragma unroll
                    for (int q = 0; q < 4; ++q) {
                        uint32_t v = vals[idxs[q]];
                        __half2 h2 = *reinterpret_cast<__half2*>(&v);
                        acc0 = fmaf(__low2float(h2), wts[q], acc0);
                        acc1 = fmaf(__high2float(h2), wts[q], acc1);
                    }
                }
            }

            float s0 = 1.0f / (1.0f + __expf(-SCALE * acc0));
            float s1 = 1.0f / (1.0f + __expf(-SCALE * acc1));

            if (l < NLAY - 1) {
                __half2 h2 = __floats2half2_rn(s0, s1);
                vals[base + l * M_SZ + m] = *reinterpret_cast<uint32_t*>(&h2);
            } else {
                out[(size_t)b0 * M_SZ + m]       = s0;
                out[(size_t)(b0 + 1) * M_SZ + m] = s1;
            }
        }
        __syncthreads();
    }
}

extern "C" void kernel_launch(void* const* d_in, const int* in_sizes, int n_in,
                              void* d_out, int out_size, void* d_ws, size_t ws_size,
                              hipStream_t stream) {
    const float* x        = (const float*)d_in[0];
    const float* W        = (const float*)d_in[1];
    const int*   edge_idx = (const int*)d_in[2];
    float*       out      = (float*)d_out;

    const int n = NLAY * M_SZ * K_SZ;  // 524288 packed words = 2 MB
    if (ws_size >= (size_t)n * sizeof(uint32_t)) {
        uint32_t* packed = (uint32_t*)d_ws;
        pack_kernel<<<(n + 255) / 256, 256, 0, stream>>>(edge_idx, W, packed, n);
        ffn_kernel<true><<<B_SZ / 2, TPB, 0, stream>>>(x, packed, nullptr, nullptr, out);
    } else {
        ffn_kernel<false><<<B_SZ / 2, TPB, 0, stream>>>(x, nullptr, edge_idx, W, out);
    }
}